// Round 4
// baseline (1318.160 us; speedup 1.0000x reference)
//
#include <hip/hip_runtime.h>
#include <float.h>
#include <math.h>

// ---------------------------------------------------------------------------
// Fast activations: v_exp_f32 + v_rcp_f32 (~2-3 ulp), replacing libm calls.
// ---------------------------------------------------------------------------
__device__ __forceinline__ float fsig(float x) {
    return __builtin_amdgcn_rcpf(1.f + __expf(-x));
}
__device__ __forceinline__ float ftanh(float x) {
    // tanh(x) = 1 - 2/(1+e^{2x}); e^inf->inf->rcp 0 -> 1; e^-inf->0 -> -1.
    return 1.f - 2.f * __builtin_amdgcn_rcpf(1.f + __expf(2.f * x));
}
__device__ __forceinline__ float fact(float x, int type) {
    return (type == 2) ? ftanh(x) : fsig(x);
}
__device__ __forceinline__ float rdlane(float v, int j) {
    return __int_as_float(__builtin_amdgcn_readlane(__float_as_int(v), j));
}

// ---------------------------------------------------------------------------
// Stage 1: SPP — spatial pyramid max pool, levels (4,3,2,1) over 192x192.
// One block per (frame, channel). 192 threads: q = t/48 picks a row-triple
// of 16-row chunks (rows 48q..48q+47), c = t%48 picks a column quad
// (cols 4c..4c+3). float4 loads -> 1KB per wave-instruction (was 4B/lane
// scalar: Guideline-13 violation, suspected ~450us of round-2's gap).
// ---------------------------------------------------------------------------
__global__ __launch_bounds__(192) void spp_kernel(const float* __restrict__ frames,
                                                  float* __restrict__ pooled) {
    int bc = blockIdx.x;            // s*3 + c
    int t  = threadIdx.x;
    int q  = t / 48;                // chunk-triple 0..3 (chunks 3q..3q+2)
    int c  = t % 48;                // column-quad (cols 4c..4c+3)
    const float4* img4 = (const float4*)(frames + (size_t)bc * (192 * 192));

    __shared__ float cmall[12][192];   // per-chunk, per-column maxes
#pragma unroll
    for (int k = 0; k < 3; ++k) {
        int ch = 3 * q + k;
        float4 m = img4[(ch * 16) * 48 + c];
#pragma unroll
        for (int r = 1; r < 16; ++r) {
            float4 v = img4[(ch * 16 + r) * 48 + c];
            m.x = fmaxf(m.x, v.x); m.y = fmaxf(m.y, v.y);
            m.z = fmaxf(m.z, v.z); m.w = fmaxf(m.w, v.w);
        }
        cmall[ch][4 * c + 0] = m.x; cmall[ch][4 * c + 1] = m.y;
        cmall[ch][4 * c + 2] = m.z; cmall[ch][4 * c + 3] = m.w;
    }
    __syncthreads();

    // combine chunk maxes into the 10 row-bands (per column w = t)
    __shared__ float band[10][192];
    int w = t;
#pragma unroll
    for (int i = 0; i < 4; ++i)     // level-4 bands: 3 chunks each
        band[i][w] = fmaxf(fmaxf(cmall[3*i][w], cmall[3*i+1][w]), cmall[3*i+2][w]);
#pragma unroll
    for (int i = 0; i < 3; ++i)     // level-3 bands: 4 chunks each
        band[4+i][w] = fmaxf(fmaxf(cmall[4*i][w], cmall[4*i+1][w]),
                             fmaxf(cmall[4*i+2][w], cmall[4*i+3][w]));
#pragma unroll
    for (int i = 0; i < 2; ++i) {   // level-2 bands: 6 chunks each
        float m = cmall[6*i][w];
#pragma unroll
        for (int k = 1; k < 6; ++k) m = fmaxf(m, cmall[6*i+k][w]);
        band[7+i][w] = m;
    }
    band[9][w] = fmaxf(band[7][w], band[8][w]);   // level-1 band
    __syncthreads();

    int s = bc / 3, cch = bc % 3;
    float* orow = pooled + s * 90;
    if (t < 16) {                    // level 4: out idx c*16 + r*4 + cc
        int r = t >> 2, cc = t & 3;
        float m = -FLT_MAX;
        for (int x = cc * 48; x < cc * 48 + 48; ++x) m = fmaxf(m, band[r][x]);
        orow[cch * 16 + t] = m;
    } else if (t < 25) {             // level 3: 48 + c*9 + idx
        int idx = t - 16, r = idx / 3, cc = idx % 3;
        float m = -FLT_MAX;
        for (int x = cc * 64; x < cc * 64 + 64; ++x) m = fmaxf(m, band[4 + r][x]);
        orow[48 + cch * 9 + idx] = m;
    } else if (t < 29) {             // level 2: 75 + c*4 + idx
        int idx = t - 25, r = idx >> 1, cc = idx & 1;
        float m = -FLT_MAX;
        for (int x = cc * 96; x < cc * 96 + 96; ++x) m = fmaxf(m, band[7 + r][x]);
        orow[75 + cch * 4 + idx] = m;
    } else if (t == 29) {            // level 1: 87 + c
        float m = -FLT_MAX;
        for (int x = 0; x < 192; ++x) m = fmaxf(m, band[9][x]);
        orow[87 + cch] = m;
    }
}

// ---------------------------------------------------------------------------
// Stage 2: pooled(512,90) @ W_spp(4096,90)^T + b -> relu -> prelu(512,4096)
// ---------------------------------------------------------------------------
__global__ __launch_bounds__(256) void fc_spp_kernel(const float* __restrict__ pooled,
                                                     const float* __restrict__ W,
                                                     const float* __restrict__ b,
                                                     float* __restrict__ out) {
    int ec = blockIdx.x;
    int fc = blockIdx.y;
    int t  = threadIdx.x;
    int s0 = fc * 8;

    __shared__ __align__(16) float sp[90 * 8];
    for (int i = t; i < 720; i += 256) {
        int j = i >> 3, f = i & 7;
        sp[i] = pooled[(s0 + f) * 90 + j];
    }
    __syncthreads();

    int e0 = ec * 1024 + t;
    float acc[4][8];
#pragma unroll
    for (int k = 0; k < 4; ++k) {
        float bb = b[e0 + k * 256];
#pragma unroll
        for (int f = 0; f < 8; ++f) acc[k][f] = bb;
    }
    for (int j = 0; j < 90; ++j) {
        float w0 = W[(e0 + 0 * 256) * 90 + j];
        float w1 = W[(e0 + 1 * 256) * 90 + j];
        float w2 = W[(e0 + 2 * 256) * 90 + j];
        float w3 = W[(e0 + 3 * 256) * 90 + j];
        float4 pa = *(const float4*)&sp[j * 8 + 0];
        float4 pb = *(const float4*)&sp[j * 8 + 4];
        float pv[8] = {pa.x, pa.y, pa.z, pa.w, pb.x, pb.y, pb.z, pb.w};
#pragma unroll
        for (int f = 0; f < 8; ++f) {
            acc[0][f] += w0 * pv[f];
            acc[1][f] += w1 * pv[f];
            acc[2][f] += w2 * pv[f];
            acc[3][f] += w3 * pv[f];
        }
    }
#pragma unroll
    for (int k = 0; k < 4; ++k)
#pragma unroll
        for (int f = 0; f < 8; ++f)
            out[(size_t)(s0 + f) * 4096 + e0 + k * 256] = fmaxf(acc[k][f], 0.f);
}

// ---------------------------------------------------------------------------
// Stage 3: prelu(512,4096) @ {W_fc7,W_fcast}(64,4096)^T -> relu
// ---------------------------------------------------------------------------
__global__ __launch_bounds__(512) void fc7cast_kernel(const float* __restrict__ prelu,
                                                      const float* __restrict__ W7,
                                                      const float* __restrict__ b7,
                                                      const float* __restrict__ Wc,
                                                      const float* __restrict__ bc,
                                                      float* __restrict__ emb,
                                                      float* __restrict__ fca) {
    int blk = blockIdx.x;
    int t   = threadIdx.x;
    int s0  = blk * 4;

    __shared__ __align__(16) float pr[4 * 4096];
    const float4* src = (const float4*)(prelu + (size_t)s0 * 4096);
    float4* dst = (float4*)pr;
    for (int i = t; i < 4096; i += 512) dst[i] = src[i];
    __syncthreads();

    int o = t & 127;
    int f = t >> 7;
    const float* wr;
    float bias;
    if (o < 64) { wr = W7 + (size_t)o * 4096; bias = b7[o]; }
    else        { wr = Wc + (size_t)(o - 64) * 4096; bias = bc[o - 64]; }

    const float4* w4 = (const float4*)wr;
    const float4* p4 = (const float4*)(pr + f * 4096);
    float a0 = 0.f, a1 = 0.f, a2 = 0.f, a3 = 0.f;
    for (int j = 0; j < 1024; ++j) {
        float4 wv = w4[j];
        float4 pv = p4[j];
        a0 += wv.x * pv.x; a1 += wv.y * pv.y;
        a2 += wv.z * pv.z; a3 += wv.w * pv.w;
    }
    float a = fmaxf(a0 + a1 + a2 + a3 + bias, 0.f);
    if (o < 64) emb[(s0 + f) * 64 + o] = a;
    else        fca[(s0 + f) * 64 + (o - 64)] = a;
}

// ---------------------------------------------------------------------------
// Stage 4: gm[s][g] = Wih1[g,:]·emb[s] + bih1[g] + bhh1[g]; gf with fcast.
// ---------------------------------------------------------------------------
__global__ __launch_bounds__(256) void pregate_kernel(const float* __restrict__ emb,
                                                      const float* __restrict__ fca,
                                                      const float* __restrict__ Wih1,
                                                      const float* __restrict__ bih1,
                                                      const float* __restrict__ bhh1,
                                                      float* __restrict__ gm,
                                                      float* __restrict__ gf) {
    int s = blockIdx.x;
    int t = threadIdx.x;
    __shared__ float x[64], fx[64];
    if (t < 64) x[t] = emb[s * 64 + t];
    else if (t < 128) fx[t - 64] = fca[s * 64 + (t - 64)];
    __syncthreads();

    const float* wr = Wih1 + t * 64;
    float am = bih1[t] + bhh1[t];
    float af = am;
#pragma unroll
    for (int j = 0; j < 64; ++j) {
        float w = wr[j];
        am += w * x[j];
        af += w * fx[j];
    }
    gm[s * 256 + t] = am;
    gf[s * 256 + t] = af;
}

// ---------------------------------------------------------------------------
// Stage 5: MAIN sequential scan. ONE block, 256 threads (4 waves/4 SIMDs).
// All state (h1,c1,h2,c2) lives in REGISTERS, replicated per wave (lane j
// holds h1[j], h2[j&31]); cross-lane broadcast via v_readlane on the VALU
// (per-SIMD, parallel) instead of the CU-shared LDS unit. Only the 256 gate
// pre/post-activations cross waves through LDS. Raw s_barrier + lgkmcnt(0)
// only — trajectory global stores are fire-and-forget (no vmcnt drain).
// 2 barriers per step. __launch_bounds__(256,1): round-2 build spilled the
// 128-float weight arrays at VGPR_Count=96.
// ---------------------------------------------------------------------------
__global__ __launch_bounds__(256, 1) void lstm_main_kernel(
    const float* __restrict__ gm,
    const float* __restrict__ Whh1,
    const float* __restrict__ Wih2,
    const float* __restrict__ Whh2,
    const float* __restrict__ bih2,
    const float* __restrict__ bhh2,
    float* __restrict__ h1t, float* __restrict__ c1t,
    float* __restrict__ h2t, float* __restrict__ c2t)
{
    const int t  = threadIdx.x;
    const int l  = t & 63;
    const int wv = t >> 6;

    __shared__ float act1[256];     // cell1 post-activation gates
    __shared__ float part2[256];    // cell2 partials: [2g]=Wih2·h1+b, [2g+1]=Whh2·h2

    float wh[64];
#pragma unroll
    for (int j = 0; j < 64; ++j) wh[j] = Whh1[t * 64 + j];

    float wu[64];
    float b2 = 0.f;
    if (t < 128) {
#pragma unroll
        for (int j = 0; j < 64; ++j) wu[j] = Wih2[t * 64 + j];
        b2 = bih2[t] + bhh2[t];
    } else {
#pragma unroll
        for (int j = 0; j < 32; ++j) wu[j] = Whh2[(t - 128) * 32 + j];
#pragma unroll
        for (int j = 32; j < 64; ++j) wu[j] = 0.f;
    }

    float h1r = 0.f, c1r = 0.f;     // lane l holds element l (valid l<64)
    float h2r = 0.f, c2r = 0.f;     // lane l holds element l&31
    float gmv = gm[t];

    for (int s = 0; s < 512; ++s) {
        float gnx = (s < 511) ? gm[(s + 1) * 256 + t] : 0.f;   // prefetch

        // ---- A: cell1 gate t = gmv + Whh1[t,:]·h1 (h1 broadcast via readlane)
        {
            float a0 = gmv, a1 = 0.f, a2 = 0.f, a3 = 0.f;
#pragma unroll
            for (int j = 0; j < 64; j += 4) {
                a0 += wh[j]     * rdlane(h1r, j);
                a1 += wh[j + 1] * rdlane(h1r, j + 1);
                a2 += wh[j + 2] * rdlane(h1r, j + 2);
                a3 += wh[j + 3] * rdlane(h1r, j + 3);
            }
            act1[t] = fact((a0 + a1) + (a2 + a3), t >> 6);   // wave-uniform type
        }
        gmv = gnx;
        asm volatile("s_waitcnt lgkmcnt(0)" ::: "memory");
        __builtin_amdgcn_s_barrier();

        // ---- B: all waves redundantly update h1/c1 for element l
        {
            float iv = act1[l], fv = act1[64 + l], gv = act1[128 + l], ov = act1[192 + l];
            c1r = fv * c1r + iv * gv;
            h1r = ov * ftanh(c1r);
            if (wv == 0) {                      // fire-and-forget trajectory
                h1t[s * 64 + l] = h1r;
                c1t[s * 64 + l] = c1r;
            }
        }

        // ---- C: cell2 gate partials, K-split across wave groups
        if (t < 128) {                          // Wih2·h1_new + b2
            float p0 = b2, p1 = 0.f, p2 = 0.f, p3 = 0.f;
#pragma unroll
            for (int j = 0; j < 64; j += 4) {
                p0 += wu[j]     * rdlane(h1r, j);
                p1 += wu[j + 1] * rdlane(h1r, j + 1);
                p2 += wu[j + 2] * rdlane(h1r, j + 2);
                p3 += wu[j + 3] * rdlane(h1r, j + 3);
            }
            part2[2 * t] = (p0 + p1) + (p2 + p3);
        } else {                                // Whh2·h2_old
            int u = t - 128;
            float p0 = 0.f, p1 = 0.f, p2 = 0.f, p3 = 0.f;
#pragma unroll
            for (int k = 0; k < 32; k += 4) {
                p0 += wu[k]     * rdlane(h2r, k);
                p1 += wu[k + 1] * rdlane(h2r, k + 1);
                p2 += wu[k + 2] * rdlane(h2r, k + 2);
                p3 += wu[k + 3] * rdlane(h2r, k + 3);
            }
            part2[2 * u + 1] = (p0 + p1) + (p2 + p3);
        }
        asm volatile("s_waitcnt lgkmcnt(0)" ::: "memory");
        __builtin_amdgcn_s_barrier();

        // ---- D: all waves redundantly finish cell2 for element k = l&31
        {
            int k = l & 31;
            float2 pi = *(const float2*)&part2[2 * k];
            float2 pf = *(const float2*)&part2[2 * (32 + k)];
            float2 pg = *(const float2*)&part2[2 * (64 + k)];
            float2 po = *(const float2*)&part2[2 * (96 + k)];
            float iv = fsig(pi.x + pi.y);
            float fv = fsig(pf.x + pf.y);
            float gv = ftanh(pg.x + pg.y);
            float ov = fsig(po.x + po.y);
            c2r = fv * c2r + iv * gv;
            h2r = ov * ftanh(c2r);
            if (wv == 0 && l < 32) {            // fire-and-forget trajectory
                h2t[s * 32 + k] = h2r;
                c2t[s * 32 + k] = c2r;
            }
        }
        // no trailing barrier: next-A touches only act1 (whose reads in B are
        // ordered before next-A's writes by the C-phase barrier), and next-C's
        // part2 writes are ordered after next-A's barrier => D reads are done.
    }
}

// ---------------------------------------------------------------------------
// Stage 6: forecast branch + both heads — fully parallel over 512 steps.
// fh1 = cell1(fx_s, h1_s, c1_s); fh2 = cell2(fh1, h2_s, c2_s);  (post-update
// states). out[s] = sig(Wfc8·h2_s + b); out[512+s] = sig(Wfc8·fh2 + b).
// ---------------------------------------------------------------------------
__global__ __launch_bounds__(256) void forecast_kernel(const float* __restrict__ gf,
                                                       const float* __restrict__ Whh1,
                                                       const float* __restrict__ Wih2,
                                                       const float* __restrict__ Whh2,
                                                       const float* __restrict__ bih2,
                                                       const float* __restrict__ bhh2,
                                                       const float* __restrict__ h1t,
                                                       const float* __restrict__ c1t,
                                                       const float* __restrict__ h2t,
                                                       const float* __restrict__ c2t,
                                                       const float* __restrict__ Wfc8,
                                                       const float* __restrict__ bfc8,
                                                       float* __restrict__ out) {
    int s = blockIdx.x;
    int t = threadIdx.x;

    __shared__ __align__(16) float h1v[64];
    __shared__ __align__(16) float h2v[32];
    __shared__ __align__(16) float fh1[64];
    __shared__ float a1s[256];
    __shared__ float a2s[128];

    if (t < 64) h1v[t] = h1t[s * 64 + t];
    else if (t < 96) h2v[t - 64] = h2t[s * 32 + (t - 64)];
    __syncthreads();

    {
        const float* wr = Whh1 + t * 64;
        float a0 = 0.f, a1 = 0.f, a2 = 0.f, a3 = 0.f;
#pragma unroll
        for (int j = 0; j < 16; ++j) {
            float4 h = ((const float4*)h1v)[j];
            a0 += wr[4*j+0] * h.x; a1 += wr[4*j+1] * h.y;
            a2 += wr[4*j+2] * h.z; a3 += wr[4*j+3] * h.w;
        }
        a1s[t] = fact(gf[s * 256 + t] + ((a0 + a1) + (a2 + a3)), t >> 6);
    }
    __syncthreads();

    if (t < 64) {
        float iv = a1s[t], fv = a1s[64+t], gv = a1s[128+t], ov = a1s[192+t];
        float cf = fv * c1t[s * 64 + t] + iv * gv;
        fh1[t] = ov * ftanh(cf);
    }
    __syncthreads();

    if (t < 128) {
        const float* wi = Wih2 + t * 64;
        const float* wh = Whh2 + t * 32;
        float a0 = bih2[t] + bhh2[t], a1 = 0.f, a2 = 0.f, a3 = 0.f;
#pragma unroll
        for (int j = 0; j < 16; ++j) {
            float4 h = ((const float4*)fh1)[j];
            a0 += wi[4*j+0] * h.x; a1 += wi[4*j+1] * h.y;
            a2 += wi[4*j+2] * h.z; a3 += wi[4*j+3] * h.w;
        }
#pragma unroll
        for (int j = 0; j < 8; ++j) {
            float4 h = ((const float4*)h2v)[j];
            a0 += wh[4*j+0] * h.x; a1 += wh[4*j+1] * h.y;
            a2 += wh[4*j+2] * h.z; a3 += wh[4*j+3] * h.w;
        }
        a2s[t] = fact((a0 + a1) + (a2 + a3), (t >> 5) & 3);
    }
    __syncthreads();

    if (t < 64) {
        float pv = 0.f, fv2 = 0.f;
        if (t < 32) {
            float iv = a2s[t], fv = a2s[32+t], gv = a2s[64+t], ov = a2s[96+t];
            float cf2 = fv * c2t[s * 32 + t] + iv * gv;
            float fh2 = ov * ftanh(cf2);
            float w8 = Wfc8[t];
            pv  = w8 * h2v[t];
            fv2 = w8 * fh2;
        }
#pragma unroll
        for (int off = 16; off > 0; off >>= 1) {
            pv  += __shfl_xor(pv, off);
            fv2 += __shfl_xor(fv2, off);
        }
        if (t == 0) {
            float bf8 = bfc8[0];
            out[s]       = fsig(pv + bf8);
            out[512 + s] = fsig(fv2 + bf8);
        }
    }
}

// ---------------------------------------------------------------------------
extern "C" void kernel_launch(void* const* d_in, const int* in_sizes, int n_in,
                              void* d_out, int out_size, void* d_ws, size_t ws_size,
                              hipStream_t stream) {
    const float* frames  = (const float*)d_in[0];
    const float* W_spp   = (const float*)d_in[1];
    const float* b_spp   = (const float*)d_in[2];
    const float* W_fc7   = (const float*)d_in[3];
    const float* b_fc7   = (const float*)d_in[4];
    const float* W_fcast = (const float*)d_in[5];
    const float* b_fcast = (const float*)d_in[6];
    const float* Wih1    = (const float*)d_in[7];
    const float* Whh1    = (const float*)d_in[8];
    const float* bih1    = (const float*)d_in[9];
    const float* bhh1    = (const float*)d_in[10];
    const float* Wih2    = (const float*)d_in[11];
    const float* Whh2    = (const float*)d_in[12];
    const float* bih2    = (const float*)d_in[13];
    const float* bhh2    = (const float*)d_in[14];
    const float* W_fc8   = (const float*)d_in[15];
    const float* b_fc8   = (const float*)d_in[16];
    float* out = (float*)d_out;

    float* ws     = (float*)d_ws;
    float* pooled = ws;                       // 512*90
    float* prelu  = pooled + 512 * 90;        // 512*4096
    float* emb    = prelu + 512 * 4096;       // 512*64
    float* fca    = emb + 512 * 64;           // 512*64
    float* gm     = fca + 512 * 64;           // 512*256
    float* gf     = gm + 512 * 256;           // 512*256
    float* h1t    = gf + 512 * 256;           // 512*64
    float* c1t    = h1t + 512 * 64;           // 512*64
    float* h2t    = c1t + 512 * 64;           // 512*32
    float* c2t    = h2t + 512 * 32;           // 512*32

    spp_kernel<<<1536, 192, 0, stream>>>(frames, pooled);
    fc_spp_kernel<<<dim3(4, 64), 256, 0, stream>>>(pooled, W_spp, b_spp, prelu);
    fc7cast_kernel<<<128, 512, 0, stream>>>(prelu, W_fc7, b_fc7, W_fcast, b_fcast, emb, fca);
    pregate_kernel<<<512, 256, 0, stream>>>(emb, fca, Wih1, bih1, bhh1, gm, gf);
    lstm_main_kernel<<<1, 256, 0, stream>>>(gm, Whh1, Wih2, Whh2, bih2, bhh2,
                                            h1t, c1t, h2t, c2t);
    forecast_kernel<<<512, 256, 0, stream>>>(gf, Whh1, Wih2, Whh2, bih2, bhh2,
                                             h1t, c1t, h2t, c2t, W_fc8, b_fc8, out);
}

// Round 5
// 1311.128 us; speedup vs baseline: 1.0054x; 1.0054x over previous
//
#include <hip/hip_runtime.h>
#include <float.h>
#include <math.h>

// ---------------------------------------------------------------------------
// Fast activations: v_exp_f32 + v_rcp_f32 (~2-3 ulp), replacing libm calls.
// ---------------------------------------------------------------------------
__device__ __forceinline__ float fsig(float x) {
    return __builtin_amdgcn_rcpf(1.f + __expf(-x));
}
__device__ __forceinline__ float ftanh(float x) {
    // tanh(x) = 1 - 2/(1+e^{2x}); e^inf->inf->rcp 0 -> 1; e^-inf->0 -> -1.
    return 1.f - 2.f * __builtin_amdgcn_rcpf(1.f + __expf(2.f * x));
}
__device__ __forceinline__ float fact(float x, int type) {
    return (type == 2) ? ftanh(x) : fsig(x);
}
__device__ __forceinline__ float rdlane(float v, int j) {
    return __int_as_float(__builtin_amdgcn_readlane(__float_as_int(v), j));
}

// ---------------------------------------------------------------------------
// Stage 1: SPP — spatial pyramid max pool, levels (4,3,2,1) over 192x192.
// float4 loads; one block per (frame, channel).
// ---------------------------------------------------------------------------
__global__ __launch_bounds__(192) void spp_kernel(const float* __restrict__ frames,
                                                  float* __restrict__ pooled) {
    int bc = blockIdx.x;            // s*3 + c
    int t  = threadIdx.x;
    int q  = t / 48;                // chunk-triple 0..3 (chunks 3q..3q+2)
    int c  = t % 48;                // column-quad (cols 4c..4c+3)
    const float4* img4 = (const float4*)(frames + (size_t)bc * (192 * 192));

    __shared__ float cmall[12][192];   // per-chunk, per-column maxes
#pragma unroll
    for (int k = 0; k < 3; ++k) {
        int ch = 3 * q + k;
        float4 m = img4[(ch * 16) * 48 + c];
#pragma unroll
        for (int r = 1; r < 16; ++r) {
            float4 v = img4[(ch * 16 + r) * 48 + c];
            m.x = fmaxf(m.x, v.x); m.y = fmaxf(m.y, v.y);
            m.z = fmaxf(m.z, v.z); m.w = fmaxf(m.w, v.w);
        }
        cmall[ch][4 * c + 0] = m.x; cmall[ch][4 * c + 1] = m.y;
        cmall[ch][4 * c + 2] = m.z; cmall[ch][4 * c + 3] = m.w;
    }
    __syncthreads();

    __shared__ float band[10][192];
    int w = t;
#pragma unroll
    for (int i = 0; i < 4; ++i)
        band[i][w] = fmaxf(fmaxf(cmall[3*i][w], cmall[3*i+1][w]), cmall[3*i+2][w]);
#pragma unroll
    for (int i = 0; i < 3; ++i)
        band[4+i][w] = fmaxf(fmaxf(cmall[4*i][w], cmall[4*i+1][w]),
                             fmaxf(cmall[4*i+2][w], cmall[4*i+3][w]));
#pragma unroll
    for (int i = 0; i < 2; ++i) {
        float m = cmall[6*i][w];
#pragma unroll
        for (int k = 1; k < 6; ++k) m = fmaxf(m, cmall[6*i+k][w]);
        band[7+i][w] = m;
    }
    band[9][w] = fmaxf(band[7][w], band[8][w]);
    __syncthreads();

    int s = bc / 3, cch = bc % 3;
    float* orow = pooled + s * 90;
    if (t < 16) {
        int r = t >> 2, cc = t & 3;
        float m = -FLT_MAX;
        for (int x = cc * 48; x < cc * 48 + 48; ++x) m = fmaxf(m, band[r][x]);
        orow[cch * 16 + t] = m;
    } else if (t < 25) {
        int idx = t - 16, r = idx / 3, cc = idx % 3;
        float m = -FLT_MAX;
        for (int x = cc * 64; x < cc * 64 + 64; ++x) m = fmaxf(m, band[4 + r][x]);
        orow[48 + cch * 9 + idx] = m;
    } else if (t < 29) {
        int idx = t - 25, r = idx >> 1, cc = idx & 1;
        float m = -FLT_MAX;
        for (int x = cc * 96; x < cc * 96 + 96; ++x) m = fmaxf(m, band[7 + r][x]);
        orow[75 + cch * 4 + idx] = m;
    } else if (t == 29) {
        float m = -FLT_MAX;
        for (int x = 0; x < 192; ++x) m = fmaxf(m, band[9][x]);
        orow[87 + cch] = m;
    }
}

// ---------------------------------------------------------------------------
// Stage 2: pooled(512,90) @ W_spp(4096,90)^T + b -> relu -> prelu(512,4096)
// ---------------------------------------------------------------------------
__global__ __launch_bounds__(256) void fc_spp_kernel(const float* __restrict__ pooled,
                                                     const float* __restrict__ W,
                                                     const float* __restrict__ b,
                                                     float* __restrict__ out) {
    int ec = blockIdx.x;
    int fc = blockIdx.y;
    int t  = threadIdx.x;
    int s0 = fc * 8;

    __shared__ __align__(16) float sp[90 * 8];
    for (int i = t; i < 720; i += 256) {
        int j = i >> 3, f = i & 7;
        sp[i] = pooled[(s0 + f) * 90 + j];
    }
    __syncthreads();

    int e0 = ec * 1024 + t;
    float acc[4][8];
#pragma unroll
    for (int k = 0; k < 4; ++k) {
        float bb = b[e0 + k * 256];
#pragma unroll
        for (int f = 0; f < 8; ++f) acc[k][f] = bb;
    }
    for (int j = 0; j < 90; ++j) {
        float w0 = W[(e0 + 0 * 256) * 90 + j];
        float w1 = W[(e0 + 1 * 256) * 90 + j];
        float w2 = W[(e0 + 2 * 256) * 90 + j];
        float w3 = W[(e0 + 3 * 256) * 90 + j];
        float4 pa = *(const float4*)&sp[j * 8 + 0];
        float4 pb = *(const float4*)&sp[j * 8 + 4];
        float pv[8] = {pa.x, pa.y, pa.z, pa.w, pb.x, pb.y, pb.z, pb.w};
#pragma unroll
        for (int f = 0; f < 8; ++f) {
            acc[0][f] += w0 * pv[f];
            acc[1][f] += w1 * pv[f];
            acc[2][f] += w2 * pv[f];
            acc[3][f] += w3 * pv[f];
        }
    }
#pragma unroll
    for (int k = 0; k < 4; ++k)
#pragma unroll
        for (int f = 0; f < 8; ++f)
            out[(size_t)(s0 + f) * 4096 + e0 + k * 256] = fmaxf(acc[k][f], 0.f);
}

// ---------------------------------------------------------------------------
// Stage 3: prelu(512,4096) @ {W_fc7,W_fcast}(64,4096)^T -> relu
// ---------------------------------------------------------------------------
__global__ __launch_bounds__(512) void fc7cast_kernel(const float* __restrict__ prelu,
                                                      const float* __restrict__ W7,
                                                      const float* __restrict__ b7,
                                                      const float* __restrict__ Wc,
                                                      const float* __restrict__ bc,
                                                      float* __restrict__ emb,
                                                      float* __restrict__ fca) {
    int blk = blockIdx.x;
    int t   = threadIdx.x;
    int s0  = blk * 4;

    __shared__ __align__(16) float pr[4 * 4096];
    const float4* src = (const float4*)(prelu + (size_t)s0 * 4096);
    float4* dst = (float4*)pr;
    for (int i = t; i < 4096; i += 512) dst[i] = src[i];
    __syncthreads();

    int o = t & 127;
    int f = t >> 7;
    const float* wr;
    float bias;
    if (o < 64) { wr = W7 + (size_t)o * 4096; bias = b7[o]; }
    else        { wr = Wc + (size_t)(o - 64) * 4096; bias = bc[o - 64]; }

    const float4* w4 = (const float4*)wr;
    const float4* p4 = (const float4*)(pr + f * 4096);
    float a0 = 0.f, a1 = 0.f, a2 = 0.f, a3 = 0.f;
    for (int j = 0; j < 1024; ++j) {
        float4 wv = w4[j];
        float4 pv = p4[j];
        a0 += wv.x * pv.x; a1 += wv.y * pv.y;
        a2 += wv.z * pv.z; a3 += wv.w * pv.w;
    }
    float a = fmaxf(a0 + a1 + a2 + a3 + bias, 0.f);
    if (o < 64) emb[(s0 + f) * 64 + o] = a;
    else        fca[(s0 + f) * 64 + (o - 64)] = a;
}

// ---------------------------------------------------------------------------
// Stage 4: gm[s][g] = Wih1[g,:]·emb[s] + bih1[g] + bhh1[g]; gf with fcast.
// ---------------------------------------------------------------------------
__global__ __launch_bounds__(256) void pregate_kernel(const float* __restrict__ emb,
                                                      const float* __restrict__ fca,
                                                      const float* __restrict__ Wih1,
                                                      const float* __restrict__ bih1,
                                                      const float* __restrict__ bhh1,
                                                      float* __restrict__ gm,
                                                      float* __restrict__ gf) {
    int s = blockIdx.x;
    int t = threadIdx.x;
    __shared__ float x[64], fx[64];
    if (t < 64) x[t] = emb[s * 64 + t];
    else if (t < 128) fx[t - 64] = fca[s * 64 + (t - 64)];
    __syncthreads();

    const float* wr = Wih1 + t * 64;
    float am = bih1[t] + bhh1[t];
    float af = am;
#pragma unroll
    for (int j = 0; j < 64; ++j) {
        float w = wr[j];
        am += w * x[j];
        af += w * fx[j];
    }
    gm[s * 256 + t] = am;
    gf[s * 256 + t] = af;
}

// ---------------------------------------------------------------------------
// Stage 5: MAIN sequential scan. ONE block, 256 threads (4 waves/4 SIMDs).
// ROUND-5 FIX: rounds 2-4 had VGPR_Count=92-96 — the backend's occupancy
// heuristic rematerialized the ~112 weight loads INSIDE the 512-step loop
// (L2 round-trip per weight per step = the ~2500 unexplained cyc/step).
// __launch_bounds__(256,1) only PERMITS low occupancy; it doesn't change the
// regalloc target. amdgpu_waves_per_eu(1,1) forces it (512-VGPR budget), and
// the weights are macro-expanded NAMED float4s so SROA can't fail.
// Expect VGPR_Count >= 160. Only 1 block runs -> 1 wave/EU is exact.
// ---------------------------------------------------------------------------
#define REP16(M) M(0) M(1) M(2) M(3) M(4) M(5) M(6) M(7) \
                 M(8) M(9) M(10) M(11) M(12) M(13) M(14) M(15)
#define REP8(M)  M(0) M(1) M(2) M(3) M(4) M(5) M(6) M(7)

__global__ __launch_bounds__(256)
__attribute__((amdgpu_waves_per_eu(1, 1)))
void lstm_main_kernel(
    const float* __restrict__ gm,
    const float* __restrict__ Whh1,
    const float* __restrict__ Wih2,
    const float* __restrict__ Whh2,
    const float* __restrict__ bih2,
    const float* __restrict__ bhh2,
    float* __restrict__ h1t, float* __restrict__ c1t,
    float* __restrict__ h2t, float* __restrict__ c2t)
{
    const int t  = threadIdx.x;
    const int l  = t & 63;
    const int wv = t >> 6;

    __shared__ float act1[256];     // cell1 post-activation gates
    __shared__ float part2[256];    // cell2 partials: [2g]=Wih2·h1+b, [2g+1]=Whh2·h2

    // ---- weights in NAMED float4 registers (SROA-proof) ----
#define DWH(i) float4 wh##i;
    REP16(DWH)
#define DWU(i) float4 wu##i;
    REP16(DWU)
#undef DWH
#undef DWU

    {
        const float4* whp = (const float4*)(Whh1 + t * 64);
#define LWH(i) wh##i = whp[i];
        REP16(LWH)
#undef LWH
    }
    float b2 = 0.f;
    if (t < 128) {
        const float4* wup = (const float4*)(Wih2 + t * 64);
#define LWU(i) wu##i = wup[i];
        REP16(LWU)
#undef LWU
        b2 = bih2[t] + bhh2[t];
    } else {
        const float4* wup = (const float4*)(Whh2 + (t - 128) * 32);
#define LWV(i) wu##i = wup[i];
        REP8(LWV)
#undef LWV
        wu8 = wu9 = wu10 = wu11 = wu12 = wu13 = wu14 = wu15 = make_float4(0.f, 0.f, 0.f, 0.f);
    }

    float h1r = 0.f, c1r = 0.f;     // lane l holds element l (valid l<64)
    float h2r = 0.f, c2r = 0.f;     // lane l holds element l&31
    float gmv = gm[t];

    for (int s = 0; s < 512; ++s) {
        float gnx = (s < 511) ? gm[(s + 1) * 256 + t] : 0.f;   // prefetch

        // ---- A: cell1 gate t = gmv + Whh1[t,:]·h1 (h1 broadcast via readlane)
        {
            float a0 = gmv, a1 = 0.f, a2 = 0.f, a3 = 0.f;
#define FA(i) a0 += wh##i.x * rdlane(h1r, 4*i+0); \
              a1 += wh##i.y * rdlane(h1r, 4*i+1); \
              a2 += wh##i.z * rdlane(h1r, 4*i+2); \
              a3 += wh##i.w * rdlane(h1r, 4*i+3);
            REP16(FA)
#undef FA
            act1[t] = fact((a0 + a1) + (a2 + a3), t >> 6);   // wave-uniform type
        }
        gmv = gnx;
        asm volatile("s_waitcnt lgkmcnt(0)" ::: "memory");
        __builtin_amdgcn_s_barrier();

        // ---- B: all waves redundantly update h1/c1 for element l
        {
            float iv = act1[l], fv = act1[64 + l], gv = act1[128 + l], ov = act1[192 + l];
            c1r = fv * c1r + iv * gv;
            h1r = ov * ftanh(c1r);
            if (wv == 0) {                      // fire-and-forget trajectory
                h1t[s * 64 + l] = h1r;
                c1t[s * 64 + l] = c1r;
            }
        }

        // ---- C: cell2 gate partials, K-split across wave groups
        if (t < 128) {                          // Wih2·h1_new + b2
            float p0 = b2, p1 = 0.f, p2 = 0.f, p3 = 0.f;
#define FU(i) p0 += wu##i.x * rdlane(h1r, 4*i+0); \
              p1 += wu##i.y * rdlane(h1r, 4*i+1); \
              p2 += wu##i.z * rdlane(h1r, 4*i+2); \
              p3 += wu##i.w * rdlane(h1r, 4*i+3);
            REP16(FU)
#undef FU
            part2[2 * t] = (p0 + p1) + (p2 + p3);
        } else {                                // Whh2·h2_old
            int u = t - 128;
            float p0 = 0.f, p1 = 0.f, p2 = 0.f, p3 = 0.f;
#define FV(i) p0 += wu##i.x * rdlane(h2r, 4*i+0); \
              p1 += wu##i.y * rdlane(h2r, 4*i+1); \
              p2 += wu##i.z * rdlane(h2r, 4*i+2); \
              p3 += wu##i.w * rdlane(h2r, 4*i+3);
            REP8(FV)
#undef FV
            part2[2 * u + 1] = (p0 + p1) + (p2 + p3);
        }
        asm volatile("s_waitcnt lgkmcnt(0)" ::: "memory");
        __builtin_amdgcn_s_barrier();

        // ---- D: all waves redundantly finish cell2 for element k = l&31
        {
            int k = l & 31;
            float2 pi = *(const float2*)&part2[2 * k];
            float2 pf = *(const float2*)&part2[2 * (32 + k)];
            float2 pg = *(const float2*)&part2[2 * (64 + k)];
            float2 po = *(const float2*)&part2[2 * (96 + k)];
            float iv = fsig(pi.x + pi.y);
            float fv = fsig(pf.x + pf.y);
            float gv = ftanh(pg.x + pg.y);
            float ov = fsig(po.x + po.y);
            c2r = fv * c2r + iv * gv;
            h2r = ov * ftanh(c2r);
            if (wv == 0 && l < 32) {            // fire-and-forget trajectory
                h2t[s * 32 + k] = h2r;
                c2t[s * 32 + k] = c2r;
            }
        }
        // no trailing barrier: D's part2 reads complete before next-A's barrier,
        // and next-C's part2 writes are ordered after that barrier.
    }
}

// ---------------------------------------------------------------------------
// Stage 6: forecast branch + both heads — fully parallel over 512 steps.
// ---------------------------------------------------------------------------
__global__ __launch_bounds__(256) void forecast_kernel(const float* __restrict__ gf,
                                                       const float* __restrict__ Whh1,
                                                       const float* __restrict__ Wih2,
                                                       const float* __restrict__ Whh2,
                                                       const float* __restrict__ bih2,
                                                       const float* __restrict__ bhh2,
                                                       const float* __restrict__ h1t,
                                                       const float* __restrict__ c1t,
                                                       const float* __restrict__ h2t,
                                                       const float* __restrict__ c2t,
                                                       const float* __restrict__ Wfc8,
                                                       const float* __restrict__ bfc8,
                                                       float* __restrict__ out) {
    int s = blockIdx.x;
    int t = threadIdx.x;

    __shared__ __align__(16) float h1v[64];
    __shared__ __align__(16) float h2v[32];
    __shared__ __align__(16) float fh1[64];
    __shared__ float a1s[256];
    __shared__ float a2s[128];

    if (t < 64) h1v[t] = h1t[s * 64 + t];
    else if (t < 96) h2v[t - 64] = h2t[s * 32 + (t - 64)];
    __syncthreads();

    {
        const float* wr = Whh1 + t * 64;
        float a0 = 0.f, a1 = 0.f, a2 = 0.f, a3 = 0.f;
#pragma unroll
        for (int j = 0; j < 16; ++j) {
            float4 h = ((const float4*)h1v)[j];
            a0 += wr[4*j+0] * h.x; a1 += wr[4*j+1] * h.y;
            a2 += wr[4*j+2] * h.z; a3 += wr[4*j+3] * h.w;
        }
        a1s[t] = fact(gf[s * 256 + t] + ((a0 + a1) + (a2 + a3)), t >> 6);
    }
    __syncthreads();

    if (t < 64) {
        float iv = a1s[t], fv = a1s[64+t], gv = a1s[128+t], ov = a1s[192+t];
        float cf = fv * c1t[s * 64 + t] + iv * gv;
        fh1[t] = ov * ftanh(cf);
    }
    __syncthreads();

    if (t < 128) {
        const float* wi = Wih2 + t * 64;
        const float* wh = Whh2 + t * 32;
        float a0 = bih2[t] + bhh2[t], a1 = 0.f, a2 = 0.f, a3 = 0.f;
#pragma unroll
        for (int j = 0; j < 16; ++j) {
            float4 h = ((const float4*)fh1)[j];
            a0 += wi[4*j+0] * h.x; a1 += wi[4*j+1] * h.y;
            a2 += wi[4*j+2] * h.z; a3 += wi[4*j+3] * h.w;
        }
#pragma unroll
        for (int j = 0; j < 8; ++j) {
            float4 h = ((const float4*)h2v)[j];
            a0 += wh[4*j+0] * h.x; a1 += wh[4*j+1] * h.y;
            a2 += wh[4*j+2] * h.z; a3 += wh[4*j+3] * h.w;
        }
        a2s[t] = fact((a0 + a1) + (a2 + a3), (t >> 5) & 3);
    }
    __syncthreads();

    if (t < 64) {
        float pv = 0.f, fv2 = 0.f;
        if (t < 32) {
            float iv = a2s[t], fv = a2s[32+t], gv = a2s[64+t], ov = a2s[96+t];
            float cf2 = fv * c2t[s * 32 + t] + iv * gv;
            float fh2 = ov * ftanh(cf2);
            float w8 = Wfc8[t];
            pv  = w8 * h2v[t];
            fv2 = w8 * fh2;
        }
#pragma unroll
        for (int off = 16; off > 0; off >>= 1) {
            pv  += __shfl_xor(pv, off);
            fv2 += __shfl_xor(fv2, off);
        }
        if (t == 0) {
            float bf8 = bfc8[0];
            out[s]       = fsig(pv + bf8);
            out[512 + s] = fsig(fv2 + bf8);
        }
    }
}

// ---------------------------------------------------------------------------
extern "C" void kernel_launch(void* const* d_in, const int* in_sizes, int n_in,
                              void* d_out, int out_size, void* d_ws, size_t ws_size,
                              hipStream_t stream) {
    const float* frames  = (const float*)d_in[0];
    const float* W_spp   = (const float*)d_in[1];
    const float* b_spp   = (const float*)d_in[2];
    const float* W_fc7   = (const float*)d_in[3];
    const float* b_fc7   = (const float*)d_in[4];
    const float* W_fcast = (const float*)d_in[5];
    const float* b_fcast = (const float*)d_in[6];
    const float* Wih1    = (const float*)d_in[7];
    const float* Whh1    = (const float*)d_in[8];
    const float* bih1    = (const float*)d_in[9];
    const float* bhh1    = (const float*)d_in[10];
    const float* Wih2    = (const float*)d_in[11];
    const float* Whh2    = (const float*)d_in[12];
    const float* bih2    = (const float*)d_in[13];
    const float* bhh2    = (const float*)d_in[14];
    const float* W_fc8   = (const float*)d_in[15];
    const float* b_fc8   = (const float*)d_in[16];
    float* out = (float*)d_out;

    float* ws     = (float*)d_ws;
    float* pooled = ws;                       // 512*90
    float* prelu  = pooled + 512 * 90;        // 512*4096
    float* emb    = prelu + 512 * 4096;       // 512*64
    float* fca    = emb + 512 * 64;           // 512*64
    float* gm     = fca + 512 * 64;           // 512*256
    float* gf     = gm + 512 * 256;           // 512*256
    float* h1t    = gf + 512 * 256;           // 512*64
    float* c1t    = h1t + 512 * 64;           // 512*64
    float* h2t    = c1t + 512 * 64;           // 512*32
    float* c2t    = h2t + 512 * 32;           // 512*32

    spp_kernel<<<1536, 192, 0, stream>>>(frames, pooled);
    fc_spp_kernel<<<dim3(4, 64), 256, 0, stream>>>(pooled, W_spp, b_spp, prelu);
    fc7cast_kernel<<<128, 512, 0, stream>>>(prelu, W_fc7, b_fc7, W_fcast, b_fcast, emb, fca);
    pregate_kernel<<<512, 256, 0, stream>>>(emb, fca, Wih1, bih1, bhh1, gm, gf);
    lstm_main_kernel<<<1, 256, 0, stream>>>(gm, Whh1, Wih2, Whh2, bih2, bhh2,
                                            h1t, c1t, h2t, c2t);
    forecast_kernel<<<512, 256, 0, stream>>>(gf, Whh1, Wih2, Whh2, bih2, bhh2,
                                             h1t, c1t, h2t, c2t, W_fc8, b_fc8, out);
}